// Round 1
// baseline (289.926 us; speedup 1.0000x reference)
//
#include <hip/hip_runtime.h>

typedef unsigned short ushort_t;
typedef __attribute__((ext_vector_type(8))) short bf16x8;   // 8 bf16 in 4 VGPRs
typedef __attribute__((ext_vector_type(4))) float f32x4;

__device__ __forceinline__ unsigned short f2bf(float f) {
    union { float f; unsigned u; } v; v.f = f;
    unsigned r = v.u + 0x7FFFu + ((v.u >> 16) & 1u);   // RNE
    return (unsigned short)(r >> 16);
}

// async global->LDS, 16B per lane; lds ptr must be wave-uniform (lane i -> base + i*16)
__device__ __forceinline__ void gl_lds16(const void* g, void* l) {
    __builtin_amdgcn_global_load_lds(
        (const __attribute__((address_space(1))) unsigned int*)g,
        (__attribute__((address_space(3))) unsigned int*)l, 16, 0, 0);
}

// ---------------- weight prep: fp32 -> bf16 (+padding) ----------------
__global__ __launch_bounds__(256) void prep_w1(const float* __restrict__ w, ushort_t* __restrict__ W1) {
    int idx = blockIdx.x * 256 + threadIdx.x;           // over 512*704
    if (idx >= 512 * 704) return;
    int n = idx / 704, k = idx % 704;
    W1[idx] = (k < 676) ? f2bf(w[n * 676 + k]) : (ushort_t)0;
}
__global__ __launch_bounds__(256) void prep_w2(const float* __restrict__ w, ushort_t* __restrict__ W2) {
    int idx = blockIdx.x * 256 + threadIdx.x;           // over 512*512
    W2[idx] = f2bf(w[idx]);
}
__global__ __launch_bounds__(256) void prep_w3(const float* __restrict__ w, ushort_t* __restrict__ W3) {
    int idx = blockIdx.x * 256 + threadIdx.x;           // over 16*512
    if (idx >= 16 * 512) return;
    W3[idx] = (idx < 10 * 512) ? f2bf(w[idx]) : (ushort_t)0;
}

// ---------------- conv 3x3 valid + cast to bf16, pad K 676->704 ----------------
__global__ __launch_bounds__(256) void conv_kernel(const float* __restrict__ x,
                                                   const float* __restrict__ cw,
                                                   ushort_t* __restrict__ h) {
    int c = blockIdx.y * 256 + threadIdx.x;
    if (c >= 704) return;
    int m = blockIdx.x;
    float v = 0.f;
    if (c < 676) {
        int r = c / 26, col = c % 26;
        const float* xr = x + (size_t)m * 784 + r * 28 + col;
#pragma unroll
        for (int dr = 0; dr < 3; ++dr)
#pragma unroll
            for (int dc = 0; dc < 3; ++dc)
                v += xr[dr * 28 + dc] * cw[dr * 3 + dc];
        h[(size_t)m * 704 + c] = f2bf(v);
    } else {
        h[(size_t)m * 704 + c] = 0;   // zero padding so MFMA K-tail contributes 0
    }
}

// ---------------- main GEMM: C[m][n] = act(sum_k A[m][k]*W[n][k] + bias[n]) ----------------
// 128x128 block tile, 4 waves (2x2) of 64x64, BK=64, global_load_lds staging with
// XOR seg swizzle (seg_store = seg_global ^ (row&7)) -> conflict-free-ish ds_read_b128.
template <int LDA, int KSTEPS, bool RELU>
__global__ __launch_bounds__(256) void gemm_bias_act(const ushort_t* __restrict__ A,
                                                     const ushort_t* __restrict__ W,
                                                     const float* __restrict__ bias,
                                                     ushort_t* __restrict__ C) {
    __shared__ ushort_t As[128 * 64];
    __shared__ ushort_t Bs[128 * 64];
    const int tid = threadIdx.x;
    const int wave = tid >> 6, lane = tid & 63;
    const int m0 = blockIdx.x * 128, n0 = blockIdx.y * 128;
    const int srow = lane >> 3;            // row within 8-row group
    const int sseg = lane & 7;             // stored 16B-seg position
    const int gseg = sseg ^ (srow & 7);    // which global seg this lane fetches
    const int wm = wave >> 1, wn = wave & 1;
    const int quad = lane >> 4, l16 = lane & 15;
    f32x4 acc[4][4] = {};

    for (int ks = 0; ks < KSTEPS; ++ks) {
        const int k0 = ks * 64;
#pragma unroll
        for (int t = 0; t < 4; ++t) {
            const int r0 = wave * 32 + t * 8;       // wave-uniform
            const int row = r0 + srow;
            gl_lds16(A + (size_t)(m0 + row) * LDA + k0 + gseg * 8, &As[r0 * 64]);
            gl_lds16(W + (size_t)(n0 + row) * LDA + k0 + gseg * 8, &Bs[r0 * 64]);
        }
        __syncthreads();
#pragma unroll
        for (int kk = 0; kk < 2; ++kk) {
            const int q = kk * 4 + quad;            // 16B seg within the 64-col tile
            bf16x8 af[4], bfr[4];
#pragma unroll
            for (int i = 0; i < 4; ++i) {
                const int mr = wm * 64 + i * 16 + l16;
                af[i] = *(const bf16x8*)&As[mr * 64 + ((q ^ (mr & 7)) * 8)];
                const int nr = wn * 64 + i * 16 + l16;
                bfr[i] = *(const bf16x8*)&Bs[nr * 64 + ((q ^ (nr & 7)) * 8)];
            }
#pragma unroll
            for (int i = 0; i < 4; ++i)
#pragma unroll
                for (int j = 0; j < 4; ++j)
                    acc[i][j] = __builtin_amdgcn_mfma_f32_16x16x32_bf16(af[i], bfr[j], acc[i][j], 0, 0, 0);
        }
        __syncthreads();
    }

    // epilogue: bias + relu + bf16 store. C/D layout: col = lane&15, row = quad*4 + r
#pragma unroll
    for (int j = 0; j < 4; ++j) {
        const int n = n0 + wn * 64 + j * 16 + l16;
        const float bb = bias[n];
#pragma unroll
        for (int i = 0; i < 4; ++i) {
            const int mb = m0 + wm * 64 + i * 16 + quad * 4;
#pragma unroll
            for (int r = 0; r < 4; ++r) {
                float v = acc[i][j][r] + bb;
                if (RELU) v = fmaxf(v, 0.0f);
                C[(size_t)(mb + r) * 512 + n] = f2bf(v);
            }
        }
    }
}

// ---------------- head: out[m][n<10] = sum_k h2[m][k]*W3[n][k] + ob[n] ----------------
__global__ __launch_bounds__(256) void head_gemm(const ushort_t* __restrict__ h2,
                                                 const ushort_t* __restrict__ W3,
                                                 const float* __restrict__ ob,
                                                 float* __restrict__ out) {
    __shared__ ushort_t Bs[16 * 520];                   // +8 pad to dodge bank conflicts
    const int tid = threadIdx.x;
    for (int i = tid; i < 16 * 512; i += 256)
        Bs[(i >> 9) * 520 + (i & 511)] = W3[i];
    __syncthreads();
    const int wave = tid >> 6, lane = tid & 63;
    const int quad = lane >> 4, l16 = lane & 15;
    const int m0 = blockIdx.x * 64 + wave * 16;
    f32x4 acc = {0.f, 0.f, 0.f, 0.f};
#pragma unroll
    for (int ks = 0; ks < 16; ++ks) {
        bf16x8 a = *(const bf16x8*)&h2[(size_t)(m0 + l16) * 512 + ks * 32 + quad * 8];
        bf16x8 b = *(const bf16x8*)&Bs[l16 * 520 + ks * 32 + quad * 8];
        acc = __builtin_amdgcn_mfma_f32_16x16x32_bf16(a, b, acc, 0, 0, 0);
    }
    if (l16 < 10) {
        const float bb = ob[l16];
#pragma unroll
        for (int r = 0; r < 4; ++r)
            out[(size_t)(m0 + quad * 4 + r) * 10 + l16] = acc[r] + bb;
    }
}

extern "C" void kernel_launch(void* const* d_in, const int* in_sizes, int n_in,
                              void* d_out, int out_size, void* d_ws, size_t ws_size,
                              hipStream_t stream) {
    const float* x      = (const float*)d_in[0];
    const float* conv_w = (const float*)d_in[1];
    const float* fc1_w  = (const float*)d_in[2];
    const float* fc1_b  = (const float*)d_in[3];
    const float* fc2_w  = (const float*)d_in[4];
    const float* fc2_b  = (const float*)d_in[5];
    const float* out_w  = (const float*)d_in[6];
    const float* out_b  = (const float*)d_in[7];
    float* out = (float*)d_out;

    // workspace layout (all 16B aligned): W1 | W2 | W3 | h (later reused as h2) | h1
    ushort_t* W1 = (ushort_t*)d_ws;                    // 512*704
    ushort_t* W2 = W1 + 512 * 704;                     // 512*512
    ushort_t* W3 = W2 + 512 * 512;                     // 16*512
    ushort_t* h  = W3 + 16 * 512;                      // 32768*704 bf16
    ushort_t* h1 = h + (size_t)32768 * 704;            // 32768*512 bf16
    ushort_t* h2 = h;                                  // alias: h dead after gemm1

    prep_w1<<<dim3((512 * 704 + 255) / 256), 256, 0, stream>>>(fc1_w, W1);
    prep_w2<<<dim3((512 * 512) / 256), 256, 0, stream>>>(fc2_w, W2);
    prep_w3<<<dim3(32), 256, 0, stream>>>(out_w, W3);

    conv_kernel<<<dim3(32768, 3), 256, 0, stream>>>(x, conv_w, h);

    gemm_bias_act<704, 11, true><<<dim3(256, 4), 256, 0, stream>>>(h,  W1, fc1_b, h1);
    gemm_bias_act<512, 8,  true><<<dim3(256, 4), 256, 0, stream>>>(h1, W2, fc2_b, h2);

    head_gemm<<<dim3(512), 256, 0, stream>>>(h2, W3, out_b, out);
}

// Round 2
// 251.344 us; speedup vs baseline: 1.1535x; 1.1535x over previous
//
#include <hip/hip_runtime.h>

typedef unsigned short ushort_t;
typedef __attribute__((ext_vector_type(8))) short bf16x8;   // 8 bf16 in 4 VGPRs
typedef __attribute__((ext_vector_type(4))) float f32x4;

__device__ __forceinline__ unsigned short f2bf(float f) {
    union { float f; unsigned u; } v; v.f = f;
    unsigned r = v.u + 0x7FFFu + ((v.u >> 16) & 1u);   // RNE
    return (unsigned short)(r >> 16);
}

// async global->LDS, 16B per lane; lds ptr must be wave-uniform (lane i -> base + i*16)
__device__ __forceinline__ void gl_lds16(const void* g, void* l) {
    __builtin_amdgcn_global_load_lds(
        (const __attribute__((address_space(1))) unsigned int*)g,
        (__attribute__((address_space(3))) unsigned int*)l, 16, 0, 0);
}

// ---------------- fold conv into fc1: W1eff[n,p] = sum cw[dr,dc]*fc1_w[n,(pr-dr)*26+(pc-dc)] ----------------
// W1eff is [512, 832] bf16 (p >= 784 zero-padded for BK=64 tiling).
__global__ __launch_bounds__(256) void prep_w1eff(const float* __restrict__ fc1_w,
                                                  const float* __restrict__ cw,
                                                  ushort_t* __restrict__ W1) {
    int idx = blockIdx.x * 256 + threadIdx.x;           // over 512*832
    if (idx >= 512 * 832) return;
    int n = idx / 832, p = idx % 832;
    float acc = 0.f;
    if (p < 784) {
        int pr = p / 28, pc = p % 28;
#pragma unroll
        for (int dr = 0; dr < 3; ++dr) {
            int r = pr - dr;
            if (r < 0 || r >= 26) continue;
#pragma unroll
            for (int dc = 0; dc < 3; ++dc) {
                int col = pc - dc;
                if (col < 0 || col >= 26) continue;
                acc += cw[dr * 3 + dc] * fc1_w[n * 676 + r * 26 + col];
            }
        }
    }
    W1[idx] = f2bf(acc);                                // f2bf(0) == 0
}

__global__ __launch_bounds__(256) void prep_w2(const float* __restrict__ w, ushort_t* __restrict__ W2) {
    int idx = blockIdx.x * 256 + threadIdx.x;           // over 512*512
    W2[idx] = f2bf(w[idx]);
}
__global__ __launch_bounds__(256) void prep_w3(const float* __restrict__ w, ushort_t* __restrict__ W3) {
    int idx = blockIdx.x * 256 + threadIdx.x;           // over 16*512
    if (idx >= 16 * 512) return;
    W3[idx] = (idx < 10 * 512) ? f2bf(w[idx]) : (ushort_t)0;
}

// ---------------- streaming cast: x fp32 [32768,784] -> Xb bf16 [32768,832] (pad zeros) ----------------
__global__ __launch_bounds__(256) void cast_x(const float* __restrict__ x, ushort_t* __restrict__ Xb) {
    int idx = blockIdx.x * 256 + threadIdx.x;           // each handles 4 elems; 32768*208 total
    int m = idx / 208, j = idx % 208;
    if (m >= 32768) return;
    uint2 pack;
    if (j < 196) {
        const float4 v = *(const float4*)&x[(size_t)m * 784 + j * 4];
        pack.x = (unsigned)f2bf(v.x) | ((unsigned)f2bf(v.y) << 16);
        pack.y = (unsigned)f2bf(v.z) | ((unsigned)f2bf(v.w) << 16);
    } else {
        pack.x = 0; pack.y = 0;
    }
    *(uint2*)&Xb[(size_t)m * 832 + j * 4] = pack;
}

// ---------------- main GEMM: C[m][n] = act(sum_k A[m][k]*W[n][k] + bias[n]) ----------------
// 128x128 block tile, 4 waves (2x2) of 64x64, BK=64, global_load_lds staging with
// XOR seg swizzle (seg_store = seg_global ^ (row&7)) -> conflict-free-ish ds_read_b128.
template <int LDA, int KSTEPS, bool RELU>
__global__ __launch_bounds__(256) void gemm_bias_act(const ushort_t* __restrict__ A,
                                                     const ushort_t* __restrict__ W,
                                                     const float* __restrict__ bias,
                                                     ushort_t* __restrict__ C) {
    __shared__ ushort_t As[128 * 64];
    __shared__ ushort_t Bs[128 * 64];
    const int tid = threadIdx.x;
    const int wave = tid >> 6, lane = tid & 63;
    const int m0 = blockIdx.x * 128, n0 = blockIdx.y * 128;
    const int srow = lane >> 3;            // row within 8-row group
    const int sseg = lane & 7;             // stored 16B-seg position
    const int gseg = sseg ^ (srow & 7);    // which global seg this lane fetches
    const int wm = wave >> 1, wn = wave & 1;
    const int quad = lane >> 4, l16 = lane & 15;
    f32x4 acc[4][4] = {};

    for (int ks = 0; ks < KSTEPS; ++ks) {
        const int k0 = ks * 64;
#pragma unroll
        for (int t = 0; t < 4; ++t) {
            const int r0 = wave * 32 + t * 8;       // wave-uniform
            const int row = r0 + srow;
            gl_lds16(A + (size_t)(m0 + row) * LDA + k0 + gseg * 8, &As[r0 * 64]);
            gl_lds16(W + (size_t)(n0 + row) * LDA + k0 + gseg * 8, &Bs[r0 * 64]);
        }
        __syncthreads();
#pragma unroll
        for (int kk = 0; kk < 2; ++kk) {
            const int q = kk * 4 + quad;            // 16B seg within the 64-col tile
            bf16x8 af[4], bfr[4];
#pragma unroll
            for (int i = 0; i < 4; ++i) {
                const int mr = wm * 64 + i * 16 + l16;
                af[i] = *(const bf16x8*)&As[mr * 64 + ((q ^ (mr & 7)) * 8)];
                const int nr = wn * 64 + i * 16 + l16;
                bfr[i] = *(const bf16x8*)&Bs[nr * 64 + ((q ^ (nr & 7)) * 8)];
            }
#pragma unroll
            for (int i = 0; i < 4; ++i)
#pragma unroll
                for (int j = 0; j < 4; ++j)
                    acc[i][j] = __builtin_amdgcn_mfma_f32_16x16x32_bf16(af[i], bfr[j], acc[i][j], 0, 0, 0);
        }
        __syncthreads();
    }

    // epilogue: bias + relu + bf16 store. C/D layout: col = lane&15, row = quad*4 + r
#pragma unroll
    for (int j = 0; j < 4; ++j) {
        const int n = n0 + wn * 64 + j * 16 + l16;
        const float bb = bias[n];
#pragma unroll
        for (int i = 0; i < 4; ++i) {
            const int mb = m0 + wm * 64 + i * 16 + quad * 4;
#pragma unroll
            for (int r = 0; r < 4; ++r) {
                float v = acc[i][j][r] + bb;
                if (RELU) v = fmaxf(v, 0.0f);
                C[(size_t)(mb + r) * 512 + n] = f2bf(v);
            }
        }
    }
}

// ---------------- head: out[m][n<10] = sum_k h2[m][k]*W3[n][k] + ob[n] ----------------
__global__ __launch_bounds__(256) void head_gemm(const ushort_t* __restrict__ h2,
                                                 const ushort_t* __restrict__ W3,
                                                 const float* __restrict__ ob,
                                                 float* __restrict__ out) {
    __shared__ ushort_t Bs[16 * 520];                   // +8 pad to dodge bank conflicts
    const int tid = threadIdx.x;
    for (int i = tid; i < 16 * 512; i += 256)
        Bs[(i >> 9) * 520 + (i & 511)] = W3[i];
    __syncthreads();
    const int wave = tid >> 6, lane = tid & 63;
    const int quad = lane >> 4, l16 = lane & 15;
    const int m0 = blockIdx.x * 64 + wave * 16;
    f32x4 acc = {0.f, 0.f, 0.f, 0.f};
#pragma unroll
    for (int ks = 0; ks < 16; ++ks) {
        bf16x8 a = *(const bf16x8*)&h2[(size_t)(m0 + l16) * 512 + ks * 32 + quad * 8];
        bf16x8 b = *(const bf16x8*)&Bs[l16 * 520 + ks * 32 + quad * 8];
        acc = __builtin_amdgcn_mfma_f32_16x16x32_bf16(a, b, acc, 0, 0, 0);
    }
    if (l16 < 10) {
        const float bb = ob[l16];
#pragma unroll
        for (int r = 0; r < 4; ++r)
            out[(size_t)(m0 + quad * 4 + r) * 10 + l16] = acc[r] + bb;
    }
}

extern "C" void kernel_launch(void* const* d_in, const int* in_sizes, int n_in,
                              void* d_out, int out_size, void* d_ws, size_t ws_size,
                              hipStream_t stream) {
    const float* x      = (const float*)d_in[0];
    const float* conv_w = (const float*)d_in[1];
    const float* fc1_w  = (const float*)d_in[2];
    const float* fc1_b  = (const float*)d_in[3];
    const float* fc2_w  = (const float*)d_in[4];
    const float* fc2_b  = (const float*)d_in[5];
    const float* out_w  = (const float*)d_in[6];
    const float* out_b  = (const float*)d_in[7];
    float* out = (float*)d_out;

    // workspace layout (16B aligned): W1eff | W2 | W3 | Xb (reused as h2) | h1
    ushort_t* W1 = (ushort_t*)d_ws;                    // 512*832
    ushort_t* W2 = W1 + 512 * 832;                     // 512*512
    ushort_t* W3 = W2 + 512 * 512;                     // 16*512
    ushort_t* Xb = W3 + 16 * 512;                      // 32768*832 bf16
    ushort_t* h1 = Xb + (size_t)32768 * 832;           // 32768*512 bf16
    ushort_t* h2 = Xb;                                 // alias: Xb dead after gemm1

    prep_w1eff<<<dim3((512 * 832 + 255) / 256), 256, 0, stream>>>(fc1_w, conv_w, W1);
    prep_w2<<<dim3((512 * 512) / 256), 256, 0, stream>>>(fc2_w, W2);
    prep_w3<<<dim3(32), 256, 0, stream>>>(out_w, W3);

    cast_x<<<dim3((32768 * 208 + 255) / 256), 256, 0, stream>>>(x, Xb);

    gemm_bias_act<832, 13, true><<<dim3(256, 4), 256, 0, stream>>>(Xb, W1, fc1_b, h1);
    gemm_bias_act<512, 8,  true><<<dim3(256, 4), 256, 0, stream>>>(h1, W2, fc2_b, h2);

    head_gemm<<<dim3(512), 256, 0, stream>>>(h2, W3, out_b, out);
}

// Round 3
// 249.908 us; speedup vs baseline: 1.1601x; 1.0057x over previous
//
#include <hip/hip_runtime.h>

typedef unsigned short ushort_t;
typedef __attribute__((ext_vector_type(8))) short bf16x8;     // 8 bf16 in 4 VGPRs
typedef __attribute__((ext_vector_type(4))) float f32x4;
typedef __attribute__((ext_vector_type(16))) float f32x16;

__device__ __forceinline__ unsigned short f2bf(float f) {
    union { float f; unsigned u; } v; v.f = f;
    unsigned r = v.u + 0x7FFFu + ((v.u >> 16) & 1u);   // RNE
    return (unsigned short)(r >> 16);
}

// async global->LDS, 16B per lane; lds ptr wave-uniform, HW scatters lane i -> base + i*16
__device__ __forceinline__ void gl_lds16(const void* g, void* l) {
    __builtin_amdgcn_global_load_lds(
        (const __attribute__((address_space(1))) unsigned int*)g,
        (__attribute__((address_space(3))) unsigned int*)l, 16, 0, 0);
}

// ---------------- merged weight prep ----------------
// W1eff[n,p] = sum_{dr,dc} cw[dr,dc]*fc1_w[n,(pr-dr)*26+(pc-dc)]  (conv folded into fc1)
__global__ __launch_bounds__(256) void prep_all(const float* __restrict__ fc1_w,
                                                const float* __restrict__ cw,
                                                const float* __restrict__ fc2_w,
                                                const float* __restrict__ out_w,
                                                ushort_t* __restrict__ W1,
                                                ushort_t* __restrict__ W2,
                                                ushort_t* __restrict__ W3) {
    int idx = blockIdx.x * 256 + threadIdx.x;
    if (idx < 512 * 832) {
        int n = idx / 832, p = idx % 832;
        float acc = 0.f;
        if (p < 784) {
            int pr = p / 28, pc = p % 28;
#pragma unroll
            for (int dr = 0; dr < 3; ++dr) {
                int r = pr - dr;
                if (r < 0 || r >= 26) continue;
#pragma unroll
                for (int dc = 0; dc < 3; ++dc) {
                    int col = pc - dc;
                    if (col < 0 || col >= 26) continue;
                    acc += cw[dr * 3 + dc] * fc1_w[n * 676 + r * 26 + col];
                }
            }
        }
        W1[idx] = f2bf(acc);
    }
    if (idx < 512 * 512) W2[idx] = f2bf(fc2_w[idx]);
    if (idx < 16 * 512)  W3[idx] = (idx < 10 * 512) ? f2bf(out_w[idx]) : (ushort_t)0;
}

// ---------------- streaming cast: x fp32 [32768,784] -> Xb bf16 [32768,832] (pad zeros) ----------------
__global__ __launch_bounds__(256) void cast_x(const float* __restrict__ x, ushort_t* __restrict__ Xb) {
    int idx = blockIdx.x * 256 + threadIdx.x;           // each handles 4 elems; 32768*208 total
    int m = idx / 208, j = idx % 208;
    if (m >= 32768) return;
    uint2 pack;
    if (j < 196) {
        const float4 v = *(const float4*)&x[(size_t)m * 784 + j * 4];
        pack.x = (unsigned)f2bf(v.x) | ((unsigned)f2bf(v.y) << 16);
        pack.y = (unsigned)f2bf(v.z) | ((unsigned)f2bf(v.w) << 16);
    } else {
        pack.x = 0; pack.y = 0;
    }
    *(uint2*)&Xb[(size_t)m * 832 + j * 4] = pack;
}

// ---------------- main GEMM: C[m][n] = act(sum_k A[m][k]*W[n][k] + bias[n]) ----------------
// 128x128 block tile, 4 waves (2x2) of 64x64, BK=64. 32x32x16 MFMA (2x2 frags/wave).
// Staging via global_load_lds w=16 with XOR seg swizzle (seg_store = seg ^ (row&7)).
template <int LDA, int KSTEPS, bool RELU>
__global__ __launch_bounds__(256) void gemm_bias_act(const ushort_t* __restrict__ A,
                                                     const ushort_t* __restrict__ W,
                                                     const float* __restrict__ bias,
                                                     ushort_t* __restrict__ C) {
    __shared__ ushort_t As[128 * 64];
    __shared__ ushort_t Bs[128 * 64];
    const int tid = threadIdx.x;
    const int wave = tid >> 6, lane = tid & 63;
    const int m0 = blockIdx.x * 128, n0 = blockIdx.y * 128;
    const int srow = lane >> 3;            // row within 8-row staging group
    const int sseg = lane & 7;             // stored 16B-seg position
    const int gseg = sseg ^ (srow & 7);    // which global seg this lane fetches
    const int wm = wave >> 1, wn = wave & 1;
    const int r32 = lane & 31, half = lane >> 5;
    f32x16 acc[2][2] = {};

    for (int ks = 0; ks < KSTEPS; ++ks) {
        const int k0 = ks * 64;
#pragma unroll
        for (int t = 0; t < 4; ++t) {
            const int r0 = wave * 32 + t * 8;       // wave-uniform LDS base
            const int row = r0 + srow;
            gl_lds16(A + (size_t)(m0 + row) * LDA + k0 + gseg * 8, &As[r0 * 64]);
            gl_lds16(W + (size_t)(n0 + row) * LDA + k0 + gseg * 8, &Bs[r0 * 64]);
        }
        __syncthreads();
#pragma unroll
        for (int ksub = 0; ksub < 4; ++ksub) {      // 4 x K=16
            const int q = ksub * 2 + half;          // 16B seg within the 64-col tile
            bf16x8 af[2], bfr[2];
#pragma unroll
            for (int i = 0; i < 2; ++i) {
                const int mr = wm * 64 + i * 32 + r32;
                af[i] = *(const bf16x8*)&As[mr * 64 + ((q ^ (mr & 7)) * 8)];
                const int nr = wn * 64 + i * 32 + r32;
                bfr[i] = *(const bf16x8*)&Bs[nr * 64 + ((q ^ (nr & 7)) * 8)];
            }
#pragma unroll
            for (int i = 0; i < 2; ++i)
#pragma unroll
                for (int j = 0; j < 2; ++j)
                    acc[i][j] = __builtin_amdgcn_mfma_f32_32x32x16_bf16(af[i], bfr[j], acc[i][j], 0, 0, 0);
        }
        __syncthreads();
    }

    // epilogue: C/D layout 32x32: col = lane&31, row = (reg&3) + 8*(reg>>2) + 4*(lane>>5)
#pragma unroll
    for (int j = 0; j < 2; ++j) {
        const int n = n0 + wn * 64 + j * 32 + r32;
        const float bb = bias[n];
#pragma unroll
        for (int i = 0; i < 2; ++i) {
            const int mbase = m0 + wm * 64 + i * 32 + 4 * half;
#pragma unroll
            for (int reg = 0; reg < 16; ++reg) {
                const int row = mbase + (reg & 3) + 8 * (reg >> 2);
                float v = acc[i][j][reg] + bb;
                if (RELU) v = fmaxf(v, 0.0f);
                C[(size_t)row * 512 + n] = f2bf(v);
            }
        }
    }
}

// ---------------- head: out[m][n<10] = sum_k h2[m][k]*W3[n][k] + ob[n] ----------------
// 64 batch rows per block, h2 staged coalesced into LDS (row stride 520 elems = +16B pad
// so fragment ds_reads land 2 lanes/bank). W3 (16KB) read straight through L1.
__global__ __launch_bounds__(256) void head_gemm(const ushort_t* __restrict__ h2,
                                                 const ushort_t* __restrict__ W3,
                                                 const float* __restrict__ ob,
                                                 float* __restrict__ out) {
    __shared__ ushort_t Hs[64 * 520];
    const int tid = threadIdx.x;
    const int wave = tid >> 6, lane = tid & 63;
    const int m0 = blockIdx.x * 64;
    for (int r = wave; r < 64; r += 4)          // one gl_lds16 covers one 1KB row
        gl_lds16(h2 + (size_t)(m0 + r) * 512 + lane * 8, &Hs[r * 520]);
    __syncthreads();
    const int quad = lane >> 4, l16 = lane & 15;
    f32x4 acc = {0.f, 0.f, 0.f, 0.f};
#pragma unroll
    for (int ks = 0; ks < 16; ++ks) {
        bf16x8 a = *(const bf16x8*)&Hs[(wave * 16 + l16) * 520 + ks * 32 + quad * 8];
        bf16x8 b = *(const bf16x8*)&W3[l16 * 512 + ks * 32 + quad * 8];
        acc = __builtin_amdgcn_mfma_f32_16x16x32_bf16(a, b, acc, 0, 0, 0);
    }
    if (l16 < 10) {
        const float bb = ob[l16];
#pragma unroll
        for (int r = 0; r < 4; ++r)
            out[(size_t)(m0 + wave * 16 + quad * 4 + r) * 10 + l16] = acc[r] + bb;
    }
}

extern "C" void kernel_launch(void* const* d_in, const int* in_sizes, int n_in,
                              void* d_out, int out_size, void* d_ws, size_t ws_size,
                              hipStream_t stream) {
    const float* x      = (const float*)d_in[0];
    const float* conv_w = (const float*)d_in[1];
    const float* fc1_w  = (const float*)d_in[2];
    const float* fc1_b  = (const float*)d_in[3];
    const float* fc2_w  = (const float*)d_in[4];
    const float* fc2_b  = (const float*)d_in[5];
    const float* out_w  = (const float*)d_in[6];
    const float* out_b  = (const float*)d_in[7];
    float* out = (float*)d_out;

    // workspace layout (16B aligned): W1eff | W2 | W3 | Xb (reused as h2) | h1
    ushort_t* W1 = (ushort_t*)d_ws;                    // 512*832
    ushort_t* W2 = W1 + 512 * 832;                     // 512*512
    ushort_t* W3 = W2 + 512 * 512;                     // 16*512
    ushort_t* Xb = W3 + 16 * 512;                      // 32768*832 bf16
    ushort_t* h1 = Xb + (size_t)32768 * 832;           // 32768*512 bf16
    ushort_t* h2 = Xb;                                 // alias: Xb dead after gemm1

    prep_all<<<dim3((512 * 832 + 255) / 256), 256, 0, stream>>>(fc1_w, conv_w, fc2_w, out_w, W1, W2, W3);

    cast_x<<<dim3((32768 * 208 + 255) / 256), 256, 0, stream>>>(x, Xb);

    gemm_bias_act<832, 13, true><<<dim3(256, 4), 256, 0, stream>>>(Xb, W1, fc1_b, h1);
    gemm_bias_act<512, 8,  true><<<dim3(256, 4), 256, 0, stream>>>(h1, W2, fc2_b, h2);

    head_gemm<<<dim3(512), 256, 0, stream>>>(h2, W3, out_b, out);
}

// Round 4
// 238.741 us; speedup vs baseline: 1.2144x; 1.0468x over previous
//
#include <hip/hip_runtime.h>

typedef unsigned short ushort_t;
typedef __attribute__((ext_vector_type(8))) short bf16x8;     // 8 bf16 in 4 VGPRs
typedef __attribute__((ext_vector_type(4))) float f32x4;
typedef __attribute__((ext_vector_type(16))) float f32x16;

__device__ __forceinline__ unsigned short f2bf(float f) {
    union { float f; unsigned u; } v; v.f = f;
    unsigned r = v.u + 0x7FFFu + ((v.u >> 16) & 1u);   // RNE
    return (unsigned short)(r >> 16);
}

// async global->LDS, 16B per lane; lds ptr wave-uniform, HW scatters lane i -> base + i*16
__device__ __forceinline__ void gl_lds16(const void* g, void* l) {
    __builtin_amdgcn_global_load_lds(
        (const __attribute__((address_space(1))) unsigned int*)g,
        (__attribute__((address_space(3))) unsigned int*)l, 16, 0, 0);
}

// ================= kernel 1: all prep + x cast + out=bias init =================
// cast: x fp32 [32768,784] -> Xb bf16 [32768,832] (zero pad)  [idx < 32768*208, 4 elems each]
// W1eff[n,p] = sum cw[dr,dc]*fc1_w[n,(pr-dr)*26+(pc-dc)]      [idx < 512*832]
// W2 = bf16(fc2_w)                                             [idx < 512*512]
// W3 = bf16(out_w) padded to 16 rows                           [idx < 16*512]
// out[i] = out_b[i%10]  (head partials atomicAdd onto this)    [425984 <= idx < 753664]
__global__ __launch_bounds__(256) void prep_cast(const float* __restrict__ x,
                                                 const float* __restrict__ fc1_w,
                                                 const float* __restrict__ cw,
                                                 const float* __restrict__ fc2_w,
                                                 const float* __restrict__ out_w,
                                                 const float* __restrict__ out_b,
                                                 ushort_t* __restrict__ W1,
                                                 ushort_t* __restrict__ W2,
                                                 ushort_t* __restrict__ W3,
                                                 ushort_t* __restrict__ Xb,
                                                 float* __restrict__ out) {
    const int idx = blockIdx.x * 256 + threadIdx.x;
    // ---- streaming cast (every thread) ----
    {
        int m = idx / 208, j = idx % 208;
        if (m < 32768) {
            uint2 pack;
            if (j < 196) {
                const float4 v = *(const float4*)&x[(size_t)m * 784 + j * 4];
                pack.x = (unsigned)f2bf(v.x) | ((unsigned)f2bf(v.y) << 16);
                pack.y = (unsigned)f2bf(v.z) | ((unsigned)f2bf(v.w) << 16);
            } else {
                pack.x = 0; pack.y = 0;
            }
            *(uint2*)&Xb[(size_t)m * 832 + j * 4] = pack;
        }
    }
    // ---- W1eff (conv folded into fc1) ----
    if (idx < 512 * 832) {
        int n = idx / 832, p = idx % 832;
        float acc = 0.f;
        if (p < 784) {
            int pr = p / 28, pc = p % 28;
#pragma unroll
            for (int dr = 0; dr < 3; ++dr) {
                int r = pr - dr;
                if (r < 0 || r >= 26) continue;
#pragma unroll
                for (int dc = 0; dc < 3; ++dc) {
                    int col = pc - dc;
                    if (col < 0 || col >= 26) continue;
                    acc += cw[dr * 3 + dc] * fc1_w[n * 676 + r * 26 + col];
                }
            }
        }
        W1[idx] = f2bf(acc);
    }
    if (idx < 512 * 512) W2[idx] = f2bf(fc2_w[idx]);
    if (idx < 16 * 512)  W3[idx] = (idx < 10 * 512) ? f2bf(out_w[idx]) : (ushort_t)0;
    // ---- out = bias ----
    if (idx >= 512 * 832 && idx < 512 * 832 + 32768 * 10) {
        int i = idx - 512 * 832;
        out[i] = out_b[i % 10];
    }
}

// ================= gemm1: h1 = relu(Xb @ W1^T + b1) =================
// 128x128 tile, 4 waves (2x2) of 64x64, BK=64, 32x32x16 MFMA, gl_lds16 staging w/ XOR swizzle.
template <int LDA, int KSTEPS, bool RELU>
__global__ __launch_bounds__(256) void gemm_bias_act(const ushort_t* __restrict__ A,
                                                     const ushort_t* __restrict__ W,
                                                     const float* __restrict__ bias,
                                                     ushort_t* __restrict__ C) {
    __shared__ ushort_t As[128 * 64];
    __shared__ ushort_t Bs[128 * 64];
    const int tid = threadIdx.x;
    const int wave = tid >> 6, lane = tid & 63;
    const int m0 = blockIdx.x * 128, n0 = blockIdx.y * 128;
    const int srow = lane >> 3;
    const int sseg = lane & 7;
    const int gseg = sseg ^ (srow & 7);
    const int wm = wave >> 1, wn = wave & 1;
    const int r32 = lane & 31, half = lane >> 5;
    f32x16 acc[2][2] = {};

    for (int ks = 0; ks < KSTEPS; ++ks) {
        const int k0 = ks * 64;
#pragma unroll
        for (int t = 0; t < 4; ++t) {
            const int r0 = wave * 32 + t * 8;
            const int row = r0 + srow;
            gl_lds16(A + (size_t)(m0 + row) * LDA + k0 + gseg * 8, &As[r0 * 64]);
            gl_lds16(W + (size_t)(n0 + row) * LDA + k0 + gseg * 8, &Bs[r0 * 64]);
        }
        __syncthreads();
#pragma unroll
        for (int ksub = 0; ksub < 4; ++ksub) {
            const int q = ksub * 2 + half;
            bf16x8 af[2], bfr[2];
#pragma unroll
            for (int i = 0; i < 2; ++i) {
                const int mr = wm * 64 + i * 32 + r32;
                af[i] = *(const bf16x8*)&As[mr * 64 + ((q ^ (mr & 7)) * 8)];
                const int nr = wn * 64 + i * 32 + r32;
                bfr[i] = *(const bf16x8*)&Bs[nr * 64 + ((q ^ (nr & 7)) * 8)];
            }
#pragma unroll
            for (int i = 0; i < 2; ++i)
#pragma unroll
                for (int j = 0; j < 2; ++j)
                    acc[i][j] = __builtin_amdgcn_mfma_f32_32x32x16_bf16(af[i], bfr[j], acc[i][j], 0, 0, 0);
        }
        __syncthreads();
    }

    // epilogue: C/D 32x32 layout: col = lane&31, row = (reg&3) + 8*(reg>>2) + 4*(lane>>5)
#pragma unroll
    for (int j = 0; j < 2; ++j) {
        const int n = n0 + wn * 64 + j * 32 + r32;
        const float bb = bias[n];
#pragma unroll
        for (int i = 0; i < 2; ++i) {
            const int mbase = m0 + wm * 64 + i * 32 + 4 * half;
#pragma unroll
            for (int reg = 0; reg < 16; ++reg) {
                const int row = mbase + (reg & 3) + 8 * (reg >> 2);
                float v = acc[i][j][reg] + bb;
                if (RELU) v = fmaxf(v, 0.0f);
                C[(size_t)row * 512 + n] = f2bf(v);
            }
        }
    }
}

// ================= gemm2 + head fused =================
// C2-tile 128x128 = relu(h1 @ W2^T + b2) kept on-chip; round-trip through the staging LDS
// (C/D-layout -> A-layout, XOR-seg swizzle), then 16x16x32 MFMAs vs W3 n-slice and
// atomicAdd fp32 partials onto out (pre-initialized to out_b).
__global__ __launch_bounds__(256) void gemm2_head(const ushort_t* __restrict__ A,
                                                  const ushort_t* __restrict__ W,
                                                  const float* __restrict__ bias,
                                                  const ushort_t* __restrict__ W3,
                                                  float* __restrict__ out) {
    __shared__ ushort_t sh[128 * 128];              // 32KB: As|Bs staging, then h2-tile
    ushort_t* As = sh;
    ushort_t* Bs = sh + 128 * 64;
    const int tid = threadIdx.x;
    const int wave = tid >> 6, lane = tid & 63;
    const int m0 = blockIdx.x * 128, n0 = blockIdx.y * 128;
    const int srow = lane >> 3;
    const int sseg = lane & 7;
    const int gseg = sseg ^ (srow & 7);
    const int wm = wave >> 1, wn = wave & 1;
    const int r32 = lane & 31, half = lane >> 5;
    f32x16 acc[2][2] = {};

    for (int ks = 0; ks < 8; ++ks) {                // K = 512
        const int k0 = ks * 64;
#pragma unroll
        for (int t = 0; t < 4; ++t) {
            const int r0 = wave * 32 + t * 8;
            const int row = r0 + srow;
            gl_lds16(A + (size_t)(m0 + row) * 512 + k0 + gseg * 8, &As[r0 * 64]);
            gl_lds16(W + (size_t)(n0 + row) * 512 + k0 + gseg * 8, &Bs[r0 * 64]);
        }
        __syncthreads();
#pragma unroll
        for (int ksub = 0; ksub < 4; ++ksub) {
            const int q = ksub * 2 + half;
            bf16x8 af[2], bfr[2];
#pragma unroll
            for (int i = 0; i < 2; ++i) {
                const int mr = wm * 64 + i * 32 + r32;
                af[i] = *(const bf16x8*)&As[mr * 64 + ((q ^ (mr & 7)) * 8)];
                const int nr = wn * 64 + i * 32 + r32;
                bfr[i] = *(const bf16x8*)&Bs[nr * 64 + ((q ^ (nr & 7)) * 8)];
            }
#pragma unroll
            for (int i = 0; i < 2; ++i)
#pragma unroll
                for (int j = 0; j < 2; ++j)
                    acc[i][j] = __builtin_amdgcn_mfma_f32_32x32x16_bf16(af[i], bfr[j], acc[i][j], 0, 0, 0);
        }
        __syncthreads();                            // last iter: staging reads retired -> sh reusable
    }

    // ---- write relu'd h2-tile (bf16) into sh, row stride 128, seg' = seg ^ (row&7) ----
#pragma unroll
    for (int j = 0; j < 2; ++j) {
        const int nl = wn * 64 + j * 32 + r32;      // local col 0..127
        const float bb = bias[n0 + nl];
#pragma unroll
        for (int i = 0; i < 2; ++i) {
            const int rbase = wm * 64 + i * 32 + 4 * half;
#pragma unroll
            for (int reg = 0; reg < 16; ++reg) {
                const int row = rbase + (reg & 3) + 8 * (reg >> 2);
                const int seg = (nl >> 3) ^ (row & 7);
                sh[row * 128 + seg * 8 + (nl & 7)] = f2bf(fmaxf(acc[i][j][reg] + bb, 0.0f));
            }
        }
    }
    __syncthreads();

    // ---- head partial: out[m][0..9] += h2tile[m][:] . W3[0..9][n0:n0+128] ----
    const int quad = lane >> 4, l16 = lane & 15;
    f32x4 hacc[2] = {};
#pragma unroll
    for (int ksub = 0; ksub < 4; ++ksub) {          // K-slice = 128
        const bf16x8 b = *(const bf16x8*)&W3[l16 * 512 + n0 + ksub * 32 + quad * 8];
#pragma unroll
        for (int f = 0; f < 2; ++f) {
            const int row = wave * 32 + f * 16 + l16;
            const int seg = (ksub * 4 + quad) ^ (row & 7);
            const bf16x8 a = *(const bf16x8*)&sh[row * 128 + seg * 8];
            hacc[f] = __builtin_amdgcn_mfma_f32_16x16x32_bf16(a, b, hacc[f], 0, 0, 0);
        }
    }
    if (l16 < 10) {
#pragma unroll
        for (int f = 0; f < 2; ++f) {
            const int mb = m0 + wave * 32 + f * 16 + quad * 4;
#pragma unroll
            for (int r = 0; r < 4; ++r)
                atomicAdd(&out[(size_t)(mb + r) * 10 + l16], hacc[f][r]);
        }
    }
}

extern "C" void kernel_launch(void* const* d_in, const int* in_sizes, int n_in,
                              void* d_out, int out_size, void* d_ws, size_t ws_size,
                              hipStream_t stream) {
    const float* x      = (const float*)d_in[0];
    const float* conv_w = (const float*)d_in[1];
    const float* fc1_w  = (const float*)d_in[2];
    const float* fc1_b  = (const float*)d_in[3];
    const float* fc2_w  = (const float*)d_in[4];
    const float* fc2_b  = (const float*)d_in[5];
    const float* out_w  = (const float*)d_in[6];
    const float* out_b  = (const float*)d_in[7];
    float* out = (float*)d_out;

    // workspace: W1eff | W2 | W3 | Xb | h1
    ushort_t* W1 = (ushort_t*)d_ws;                    // 512*832
    ushort_t* W2 = W1 + 512 * 832;                     // 512*512
    ushort_t* W3 = W2 + 512 * 512;                     // 16*512
    ushort_t* Xb = W3 + 16 * 512;                      // 32768*832 bf16
    ushort_t* h1 = Xb + (size_t)32768 * 832;           // 32768*512 bf16

    prep_cast<<<dim3((32768 * 208 + 255) / 256), 256, 0, stream>>>(
        x, fc1_w, conv_w, fc2_w, out_w, out_b, W1, W2, W3, Xb, out);

    gemm_bias_act<832, 13, true><<<dim3(256, 4), 256, 0, stream>>>(Xb, W1, fc1_b, h1);

    gemm2_head<<<dim3(256, 4), 256, 0, stream>>>(h1, W2, fc2_b, W3, out);
}

// Round 5
// 235.163 us; speedup vs baseline: 1.2329x; 1.0152x over previous
//
#include <hip/hip_runtime.h>

typedef unsigned short ushort_t;
typedef __attribute__((ext_vector_type(8))) short bf16x8;     // 8 bf16 in 4 VGPRs
typedef __attribute__((ext_vector_type(4))) float f32x4;
typedef __attribute__((ext_vector_type(16))) float f32x16;

__device__ __forceinline__ unsigned short f2bf(float f) {
    union { float f; unsigned u; } v; v.f = f;
    unsigned r = v.u + 0x7FFFu + ((v.u >> 16) & 1u);   // RNE
    return (unsigned short)(r >> 16);
}

// async global->LDS, 16B per lane; lds ptr wave-uniform, HW scatters lane i -> base + i*16
__device__ __forceinline__ void gl_lds16(const void* g, void* l) {
    __builtin_amdgcn_global_load_lds(
        (const __attribute__((address_space(1))) unsigned int*)g,
        (__attribute__((address_space(3))) unsigned int*)l, 16, 0, 0);
}

// XCD-aware (m,n) block mapping: all 4 n-blocks of one m-block land on the SAME XCD
// (heuristic xcd = b%8) back-to-back, so the A-tile is pulled from L3 once per XCD and
// re-read 3x from that XCD's 4MB L2.
__device__ __forceinline__ void swizzle_mn(int b, int& m0, int& n0) {
    const int xcd = b & 7, l = b >> 3;
    n0 = (l & 3) * 128;
    m0 = ((l >> 2) * 8 + xcd) * 128;
}

// ================= kernel 1: all prep + x cast + out=bias init =================
__global__ __launch_bounds__(256) void prep_cast(const float* __restrict__ x,
                                                 const float* __restrict__ fc1_w,
                                                 const float* __restrict__ cw,
                                                 const float* __restrict__ fc2_w,
                                                 const float* __restrict__ out_w,
                                                 const float* __restrict__ out_b,
                                                 ushort_t* __restrict__ W1,
                                                 ushort_t* __restrict__ W2,
                                                 ushort_t* __restrict__ W3,
                                                 ushort_t* __restrict__ Xb,
                                                 float* __restrict__ out) {
    const int idx = blockIdx.x * 256 + threadIdx.x;
    // ---- streaming cast: x fp32 [32768,784] -> Xb bf16 [32768,832] (zero pad) ----
    {
        int m = idx / 208, j = idx % 208;
        if (m < 32768) {
            uint2 pack;
            if (j < 196) {
                const float4 v = *(const float4*)&x[(size_t)m * 784 + j * 4];
                pack.x = (unsigned)f2bf(v.x) | ((unsigned)f2bf(v.y) << 16);
                pack.y = (unsigned)f2bf(v.z) | ((unsigned)f2bf(v.w) << 16);
            } else {
                pack.x = 0; pack.y = 0;
            }
            *(uint2*)&Xb[(size_t)m * 832 + j * 4] = pack;
        }
    }
    // ---- W1eff (conv folded into fc1) ----
    if (idx < 512 * 832) {
        int n = idx / 832, p = idx % 832;
        float acc = 0.f;
        if (p < 784) {
            int pr = p / 28, pc = p % 28;
#pragma unroll
            for (int dr = 0; dr < 3; ++dr) {
                int r = pr - dr;
                if (r < 0 || r >= 26) continue;
#pragma unroll
                for (int dc = 0; dc < 3; ++dc) {
                    int col = pc - dc;
                    if (col < 0 || col >= 26) continue;
                    acc += cw[dr * 3 + dc] * fc1_w[n * 676 + r * 26 + col];
                }
            }
        }
        W1[idx] = f2bf(acc);
    }
    if (idx < 512 * 512) W2[idx] = f2bf(fc2_w[idx]);
    if (idx < 16 * 512)  W3[idx] = (idx < 10 * 512) ? f2bf(out_w[idx]) : (ushort_t)0;
    // ---- out = bias (head partials atomicAdd onto this) ----
    if (idx >= 512 * 832 && idx < 512 * 832 + 32768 * 10) {
        int i = idx - 512 * 832;
        out[i] = out_b[i % 10];
    }
}

// ================= gemm1: h1 = relu(Xb @ W1^T + b1) =================
// 128x128 tile, 4 waves (2x2) of 64x64, BK=64, 32x32x16 MFMA, gl_lds16 staging w/ XOR swizzle.
template <int LDA, int KSTEPS, bool RELU>
__global__ __launch_bounds__(256) void gemm_bias_act(const ushort_t* __restrict__ A,
                                                     const ushort_t* __restrict__ W,
                                                     const float* __restrict__ bias,
                                                     ushort_t* __restrict__ C) {
    __shared__ ushort_t As[128 * 64];
    __shared__ ushort_t Bs[128 * 64];
    const int tid = threadIdx.x;
    const int wave = tid >> 6, lane = tid & 63;
    int m0, n0;
    swizzle_mn(blockIdx.x, m0, n0);
    const int srow = lane >> 3;
    const int sseg = lane & 7;
    const int gseg = sseg ^ (srow & 7);
    const int wm = wave >> 1, wn = wave & 1;
    const int r32 = lane & 31, half = lane >> 5;
    f32x16 acc[2][2] = {};

    for (int ks = 0; ks < KSTEPS; ++ks) {
        const int k0 = ks * 64;
#pragma unroll
        for (int t = 0; t < 4; ++t) {
            const int r0 = wave * 32 + t * 8;
            const int row = r0 + srow;
            gl_lds16(A + (size_t)(m0 + row) * LDA + k0 + gseg * 8, &As[r0 * 64]);
            gl_lds16(W + (size_t)(n0 + row) * LDA + k0 + gseg * 8, &Bs[r0 * 64]);
        }
        __syncthreads();
#pragma unroll
        for (int ksub = 0; ksub < 4; ++ksub) {
            const int q = ksub * 2 + half;
            bf16x8 af[2], bfr[2];
#pragma unroll
            for (int i = 0; i < 2; ++i) {
                const int mr = wm * 64 + i * 32 + r32;
                af[i] = *(const bf16x8*)&As[mr * 64 + ((q ^ (mr & 7)) * 8)];
                const int nr = wn * 64 + i * 32 + r32;
                bfr[i] = *(const bf16x8*)&Bs[nr * 64 + ((q ^ (nr & 7)) * 8)];
            }
#pragma unroll
            for (int i = 0; i < 2; ++i)
#pragma unroll
                for (int j = 0; j < 2; ++j)
                    acc[i][j] = __builtin_amdgcn_mfma_f32_32x32x16_bf16(af[i], bfr[j], acc[i][j], 0, 0, 0);
        }
        __syncthreads();
    }

    // epilogue: C/D 32x32 layout: col = lane&31, row = (reg&3) + 8*(reg>>2) + 4*(lane>>5)
#pragma unroll
    for (int j = 0; j < 2; ++j) {
        const int n = n0 + wn * 64 + j * 32 + r32;
        const float bb = bias[n];
#pragma unroll
        for (int i = 0; i < 2; ++i) {
            const int mbase = m0 + wm * 64 + i * 32 + 4 * half;
#pragma unroll
            for (int reg = 0; reg < 16; ++reg) {
                const int row = mbase + (reg & 3) + 8 * (reg >> 2);
                float v = acc[i][j][reg] + bb;
                if (RELU) v = fmaxf(v, 0.0f);
                C[(size_t)row * 512 + n] = f2bf(v);
            }
        }
    }
}

// ================= gemm2 + head fused =================
__global__ __launch_bounds__(256) void gemm2_head(const ushort_t* __restrict__ A,
                                                  const ushort_t* __restrict__ W,
                                                  const float* __restrict__ bias,
                                                  const ushort_t* __restrict__ W3,
                                                  float* __restrict__ out) {
    __shared__ ushort_t sh[128 * 128];              // 32KB: As|Bs staging, then h2-tile
    ushort_t* As = sh;
    ushort_t* Bs = sh + 128 * 64;
    const int tid = threadIdx.x;
    const int wave = tid >> 6, lane = tid & 63;
    int m0, n0;
    swizzle_mn(blockIdx.x, m0, n0);
    const int srow = lane >> 3;
    const int sseg = lane & 7;
    const int gseg = sseg ^ (srow & 7);
    const int wm = wave >> 1, wn = wave & 1;
    const int r32 = lane & 31, half = lane >> 5;
    f32x16 acc[2][2] = {};

    for (int ks = 0; ks < 8; ++ks) {                // K = 512
        const int k0 = ks * 64;
#pragma unroll
        for (int t = 0; t < 4; ++t) {
            const int r0 = wave * 32 + t * 8;
            const int row = r0 + srow;
            gl_lds16(A + (size_t)(m0 + row) * 512 + k0 + gseg * 8, &As[r0 * 64]);
            gl_lds16(W + (size_t)(n0 + row) * 512 + k0 + gseg * 8, &Bs[r0 * 64]);
        }
        __syncthreads();
#pragma unroll
        for (int ksub = 0; ksub < 4; ++ksub) {
            const int q = ksub * 2 + half;
            bf16x8 af[2], bfr[2];
#pragma unroll
            for (int i = 0; i < 2; ++i) {
                const int mr = wm * 64 + i * 32 + r32;
                af[i] = *(const bf16x8*)&As[mr * 64 + ((q ^ (mr & 7)) * 8)];
                const int nr = wn * 64 + i * 32 + r32;
                bfr[i] = *(const bf16x8*)&Bs[nr * 64 + ((q ^ (nr & 7)) * 8)];
            }
#pragma unroll
            for (int i = 0; i < 2; ++i)
#pragma unroll
                for (int j = 0; j < 2; ++j)
                    acc[i][j] = __builtin_amdgcn_mfma_f32_32x32x16_bf16(af[i], bfr[j], acc[i][j], 0, 0, 0);
        }
        __syncthreads();
    }

    // ---- write relu'd h2-tile (bf16) into sh, row stride 128, seg' = seg ^ (row&7) ----
#pragma unroll
    for (int j = 0; j < 2; ++j) {
        const int nl = wn * 64 + j * 32 + r32;      // local col 0..127
        const float bb = bias[n0 + nl];
#pragma unroll
        for (int i = 0; i < 2; ++i) {
            const int rbase = wm * 64 + i * 32 + 4 * half;
#pragma unroll
            for (int reg = 0; reg < 16; ++reg) {
                const int row = rbase + (reg & 3) + 8 * (reg >> 2);
                const int seg = (nl >> 3) ^ (row & 7);
                sh[row * 128 + seg * 8 + (nl & 7)] = f2bf(fmaxf(acc[i][j][reg] + bb, 0.0f));
            }
        }
    }
    __syncthreads();

    // ---- head partial: out[m][0..9] += h2tile[m][:] . W3[0..9][n0:n0+128] ----
    const int quad = lane >> 4, l16 = lane & 15;
    f32x4 hacc[2] = {};
#pragma unroll
    for (int ksub = 0; ksub < 4; ++ksub) {          // K-slice = 128
        const bf16x8 b = *(const bf16x8*)&W3[l16 * 512 + n0 + ksub * 32 + quad * 8];
#pragma unroll
        for (int f = 0; f < 2; ++f) {
            const int row = wave * 32 + f * 16 + l16;
            const int seg = (ksub * 4 + quad) ^ (row & 7);
            const bf16x8 a = *(const bf16x8*)&sh[row * 128 + seg * 8];
            hacc[f] = __builtin_amdgcn_mfma_f32_16x16x32_bf16(a, b, hacc[f], 0, 0, 0);
        }
    }
    if (l16 < 10) {
#pragma unroll
        for (int f = 0; f < 2; ++f) {
            const int mb = m0 + wave * 32 + f * 16 + quad * 4;
#pragma unroll
            for (int r = 0; r < 4; ++r)
                atomicAdd(&out[(size_t)(mb + r) * 10 + l16], hacc[f][r]);
        }
    }
}

extern "C" void kernel_launch(void* const* d_in, const int* in_sizes, int n_in,
                              void* d_out, int out_size, void* d_ws, size_t ws_size,
                              hipStream_t stream) {
    const float* x      = (const float*)d_in[0];
    const float* conv_w = (const float*)d_in[1];
    const float* fc1_w  = (const float*)d_in[2];
    const float* fc1_b  = (const float*)d_in[3];
    const float* fc2_w  = (const float*)d_in[4];
    const float* fc2_b  = (const float*)d_in[5];
    const float* out_w  = (const float*)d_in[6];
    const float* out_b  = (const float*)d_in[7];
    float* out = (float*)d_out;

    // workspace: W1eff | W2 | W3 | Xb | h1
    ushort_t* W1 = (ushort_t*)d_ws;                    // 512*832
    ushort_t* W2 = W1 + 512 * 832;                     // 512*512
    ushort_t* W3 = W2 + 512 * 512;                     // 16*512
    ushort_t* Xb = W3 + 16 * 512;                      // 32768*832 bf16
    ushort_t* h1 = Xb + (size_t)32768 * 832;           // 32768*512 bf16

    prep_cast<<<dim3((32768 * 208 + 255) / 256), 256, 0, stream>>>(
        x, fc1_w, conv_w, fc2_w, out_w, out_b, W1, W2, W3, Xb, out);

    gemm_bias_act<832, 13, true><<<dim3(1024), 256, 0, stream>>>(Xb, W1, fc1_b, h1);

    gemm2_head<<<dim3(1024), 256, 0, stream>>>(h1, W2, fc2_b, W3, out);
}

// Round 6
// 230.490 us; speedup vs baseline: 1.2579x; 1.0203x over previous
//
#include <hip/hip_runtime.h>

typedef unsigned short ushort_t;
typedef __attribute__((ext_vector_type(8))) short bf16x8;     // 8 bf16 in 4 VGPRs
typedef __attribute__((ext_vector_type(4))) float f32x4;
typedef __attribute__((ext_vector_type(16))) float f32x16;

__device__ __forceinline__ unsigned short f2bf(float f) {
    union { float f; unsigned u; } v; v.f = f;
    unsigned r = v.u + 0x7FFFu + ((v.u >> 16) & 1u);   // RNE
    return (unsigned short)(r >> 16);
}

// async global->LDS, 16B per lane; lds ptr wave-uniform, HW scatters lane i -> base + i*16
__device__ __forceinline__ void gl_lds16(const void* g, void* l) {
    __builtin_amdgcn_global_load_lds(
        (const __attribute__((address_space(1))) unsigned int*)g,
        (__attribute__((address_space(3))) unsigned int*)l, 16, 0, 0);
}

// ================= weight prep =================
// W1eff[n,p] = sum cw[dr,dc]*fc1_w[n,(pr-dr)*26+(pc-dc)]   (conv folded into fc1), [512,832] pad
// W2 = bf16(fc2_w) [512,512];  W3 = bf16(out_w) padded to [16,512]
__global__ __launch_bounds__(256) void prep_w(const float* __restrict__ fc1_w,
                                              const float* __restrict__ cw,
                                              const float* __restrict__ fc2_w,
                                              const float* __restrict__ out_w,
                                              ushort_t* __restrict__ W1,
                                              ushort_t* __restrict__ W2,
                                              ushort_t* __restrict__ W3) {
    const int idx = blockIdx.x * 256 + threadIdx.x;
    if (idx < 512 * 832) {
        int n = idx / 832, p = idx % 832;
        float acc = 0.f;
        if (p < 784) {
            int pr = p / 28, pc = p % 28;
#pragma unroll
            for (int dr = 0; dr < 3; ++dr) {
                int r = pr - dr;
                if (r < 0 || r >= 26) continue;
#pragma unroll
                for (int dc = 0; dc < 3; ++dc) {
                    int col = pc - dc;
                    if (col < 0 || col >= 26) continue;
                    acc += cw[dr * 3 + dc] * fc1_w[n * 676 + r * 26 + col];
                }
            }
        }
        W1[idx] = f2bf(acc);
    }
    if (idx < 512 * 512) W2[idx] = f2bf(fc2_w[idx]);
    if (idx < 16 * 512)  W3[idx] = (idx < 10 * 512) ? f2bf(out_w[idx]) : (ushort_t)0;
}

// ================= fully-fused network =================
// One block = 64 batch rows, 512 threads (8 waves), 1 block/CU (136KB LDS).
// Phase1: h1[64][512] = relu(x @ W1eff^T + b1), acc in VGPRs (wave w owns n in [64w,64w+64)),
//         W1 staged per-BK64 via gl_lds16, x cast fp32->bf16 inline into LDS.
// Phase2: h2 = relu(h1 @ W2^T + b2), h1 read from LDS (A-layout, XOR seg swizzle).
// Phase3: out[m][0..9] = h2 @ W3^T + ob, direct stores (block owns rows exclusively).
__global__ __launch_bounds__(512, 1) void mega(const float* __restrict__ x,
                                               const ushort_t* __restrict__ W1,
                                               const ushort_t* __restrict__ W2,
                                               const ushort_t* __restrict__ W3,
                                               const float* __restrict__ b1,
                                               const float* __restrict__ b2,
                                               const float* __restrict__ ob,
                                               float* __restrict__ out) {
    extern __shared__ ushort_t smem[];
    ushort_t* xs = smem;                 // [64][64]   8 KB   x-chunk (bf16, seg-swizzled)
    ushort_t* ws = smem + 4096;          // [512][64]  64 KB  W-chunk
    ushort_t* hs = smem + 4096 + 32768;  // [64][512]  64 KB  h1 / h2 tile

    const int tid = threadIdx.x;
    const int wave = tid >> 6, lane = tid & 63;
    const int m0 = blockIdx.x * 64;
    const int srow = lane >> 3, sseg = lane & 7, gseg = sseg ^ (srow & 7);
    const int r32 = lane & 31, half = lane >> 5;
    const int xrow = tid >> 3, xoct = tid & 7;

    f32x16 acc[2][2];
#pragma unroll
    for (int i = 0; i < 2; ++i)
#pragma unroll
        for (int j = 0; j < 2; ++j)
#pragma unroll
            for (int e = 0; e < 16; ++e) acc[i][j][e] = 0.f;

    // ---------------- phase 1: K = 832, 13 steps ----------------
    for (int ks = 0; ks < 13; ++ks) {
        const int k0 = ks * 64;
#pragma unroll
        for (int t = 0; t < 8; ++t) {               // wave w stages W1 rows [64w,64w+64)
            const int rb = wave * 64 + t * 8;
            gl_lds16(W1 + (size_t)(rb + srow) * 832 + k0 + gseg * 8, &ws[rb * 64]);
        }
        {   // x-chunk: 8 floats/thread, cast+pack, swizzled ds_write_b128
            const int gc = k0 + xoct * 8;
            bf16x8 xv;
            if (gc < 784) {
                const float* xp = &x[(size_t)(m0 + xrow) * 784 + gc];
                const float4 v0 = *(const float4*)xp;
                const float4 v1 = *(const float4*)(xp + 4);
                xv[0] = (short)f2bf(v0.x); xv[1] = (short)f2bf(v0.y);
                xv[2] = (short)f2bf(v0.z); xv[3] = (short)f2bf(v0.w);
                xv[4] = (short)f2bf(v1.x); xv[5] = (short)f2bf(v1.y);
                xv[6] = (short)f2bf(v1.z); xv[7] = (short)f2bf(v1.w);
            } else {
#pragma unroll
                for (int e = 0; e < 8; ++e) xv[e] = 0;
            }
            *(bf16x8*)&xs[xrow * 64 + ((xoct ^ (xrow & 7)) * 8)] = xv;
        }
        __syncthreads();
#pragma unroll
        for (int ksub = 0; ksub < 4; ++ksub) {
            const int q = 2 * ksub + half;
            bf16x8 af[2], bw[2];
#pragma unroll
            for (int i = 0; i < 2; ++i) {
                af[i] = *(const bf16x8*)&xs[(i * 32 + r32) * 64 + ((q ^ (r32 & 7)) * 8)];
                bw[i] = *(const bf16x8*)&ws[(wave * 64 + i * 32 + r32) * 64 + ((q ^ (r32 & 7)) * 8)];
            }
#pragma unroll
            for (int i = 0; i < 2; ++i)
#pragma unroll
                for (int j = 0; j < 2; ++j)
                    acc[i][j] = __builtin_amdgcn_mfma_f32_32x32x16_bf16(af[i], bw[j], acc[i][j], 0, 0, 0);
        }
        __syncthreads();
    }

    // ---------------- h1 = relu(acc+b1) -> hs (A-layout, seg' = seg ^ (m&7)) ----------------
#pragma unroll
    for (int j = 0; j < 2; ++j) {
        const int n = wave * 64 + j * 32 + r32;
        const float bb = b1[n];
        const int nseg = n >> 3, nrem = n & 7;
#pragma unroll
        for (int i = 0; i < 2; ++i) {
#pragma unroll
            for (int reg = 0; reg < 16; ++reg) {
                const int m = i * 32 + 4 * half + (reg & 3) + 8 * (reg >> 2);
                hs[m * 512 + ((nseg ^ (m & 7)) * 8) + nrem] = f2bf(fmaxf(acc[i][j][reg] + bb, 0.f));
            }
        }
    }
#pragma unroll
    for (int i = 0; i < 2; ++i)
#pragma unroll
        for (int j = 0; j < 2; ++j)
#pragma unroll
            for (int e = 0; e < 16; ++e) acc[i][j][e] = 0.f;
    __syncthreads();

    // ---------------- phase 2: K = 512, 8 steps ----------------
    for (int ks = 0; ks < 8; ++ks) {
        const int k0 = ks * 64;
#pragma unroll
        for (int t = 0; t < 8; ++t) {
            const int rb = wave * 64 + t * 8;
            gl_lds16(W2 + (size_t)(rb + srow) * 512 + k0 + gseg * 8, &ws[rb * 64]);
        }
        __syncthreads();
#pragma unroll
        for (int ksub = 0; ksub < 4; ++ksub) {
            const int q = 2 * ksub + half;
            const int hq = 8 * ks + q;              // seg within hs row (64 segs)
            bf16x8 af[2], bw[2];
#pragma unroll
            for (int i = 0; i < 2; ++i) {
                const int m = i * 32 + r32;
                af[i] = *(const bf16x8*)&hs[m * 512 + ((hq ^ (m & 7)) * 8)];
                bw[i] = *(const bf16x8*)&ws[(wave * 64 + i * 32 + r32) * 64 + ((q ^ (r32 & 7)) * 8)];
            }
#pragma unroll
            for (int i = 0; i < 2; ++i)
#pragma unroll
                for (int j = 0; j < 2; ++j)
                    acc[i][j] = __builtin_amdgcn_mfma_f32_32x32x16_bf16(af[i], bw[j], acc[i][j], 0, 0, 0);
        }
        __syncthreads();
    }

    // ---------------- h2 = relu(acc+b2) -> hs ----------------
#pragma unroll
    for (int j = 0; j < 2; ++j) {
        const int n = wave * 64 + j * 32 + r32;
        const float bb = b2[n];
        const int nseg = n >> 3, nrem = n & 7;
#pragma unroll
        for (int i = 0; i < 2; ++i) {
#pragma unroll
            for (int reg = 0; reg < 16; ++reg) {
                const int m = i * 32 + 4 * half + (reg & 3) + 8 * (reg >> 2);
                hs[m * 512 + ((nseg ^ (m & 7)) * 8) + nrem] = f2bf(fmaxf(acc[i][j][reg] + bb, 0.f));
            }
        }
    }
    __syncthreads();

    // ---------------- head: waves 0..3, 16 rows each, K = 512 ----------------
    if (wave < 4) {
        const int quad = lane >> 4, l16 = lane & 15;
        const int row = wave * 16 + l16;
        f32x4 hacc = {0.f, 0.f, 0.f, 0.f};
#pragma unroll
        for (int ks = 0; ks < 16; ++ks) {
            const int seg = 4 * ks + quad;
            const bf16x8 a = *(const bf16x8*)&hs[row * 512 + ((seg ^ (row & 7)) * 8)];
            const bf16x8 b = *(const bf16x8*)&W3[l16 * 512 + ks * 32 + quad * 8];
            hacc = __builtin_amdgcn_mfma_f32_16x16x32_bf16(a, b, hacc, 0, 0, 0);
        }
        if (l16 < 10) {
            const float bb = ob[l16];
#pragma unroll
            for (int r = 0; r < 4; ++r)
                out[(size_t)(m0 + wave * 16 + quad * 4 + r) * 10 + l16] = hacc[r] + bb;
        }
    }
}

extern "C" void kernel_launch(void* const* d_in, const int* in_sizes, int n_in,
                              void* d_out, int out_size, void* d_ws, size_t ws_size,
                              hipStream_t stream) {
    const float* x      = (const float*)d_in[0];
    const float* conv_w = (const float*)d_in[1];
    const float* fc1_w  = (const float*)d_in[2];
    const float* fc1_b  = (const float*)d_in[3];
    const float* fc2_w  = (const float*)d_in[4];
    const float* fc2_b  = (const float*)d_in[5];
    const float* out_w  = (const float*)d_in[6];
    const float* out_b  = (const float*)d_in[7];
    float* out = (float*)d_out;

    // workspace: W1eff | W2 | W3 (≈1.4 MB total)
    ushort_t* W1 = (ushort_t*)d_ws;                    // 512*832
    ushort_t* W2 = W1 + 512 * 832;                     // 512*512
    ushort_t* W3 = W2 + 512 * 512;                     // 16*512

    prep_w<<<dim3(1664), 256, 0, stream>>>(fc1_w, conv_w, fc2_w, out_w, W1, W2, W3);

    // 512 blocks x 64 rows; 136 KB dynamic LDS -> 1 block/CU, 8 waves
    mega<<<dim3(512), 512, 139264, stream>>>(x, W1, W2, W3, fc1_b, fc2_b, out_b, out);
}